// Round 5
// baseline (1493.754 us; speedup 1.0000x reference)
//
#include <hip/hip_runtime.h>
#include <hip/hip_bf16.h>
#include <stdint.h>

// SlidingWindowAttention: x[4,4096,1024] f32, Wqkv[3072,1024] f32, Wproj[1024,1024] f32
// I/O f32; internal bf16 (MFMA) with f32 accum.
// qkv = x@Wqkv^T (q*=0.125 fused) -> per (b,h) flattened-window attention
// (256x256 over Df=1024) -> out = attn_out @ Wproj^T (f32 out).

using u16 = unsigned short;
typedef __attribute__((ext_vector_type(4))) float f32x4;
typedef __attribute__((ext_vector_type(8))) short s16x8;

#define MFMA_BF16(a, b, c) __builtin_amdgcn_mfma_f32_16x16x32_bf16((a), (b), (c), 0, 0, 0)

__device__ __forceinline__ u16 f2bf(float f) {
  union { float f; uint32_t u; } v; v.f = f;
  uint32_t r = v.u + 0x7fffu + ((v.u >> 16) & 1u);  // RNE
  return (u16)(r >> 16);
}

// async global->LDS, 16B per lane; LDS dest is wave-uniform base + lane*16
__device__ __forceinline__ void gld16(const void* g, void* l) {
  auto gp = (const __attribute__((address_space(1))) void*)(uintptr_t)g;
  auto lp = (__attribute__((address_space(3))) void*)(uint32_t)(uintptr_t)l;
  __builtin_amdgcn_global_load_lds(gp, lp, 16, 0, 0);
}

// ---------------------------------------------------------------------------
// f32 -> bf16 convert, 8 elems/thread/iter (32B in, 16B out)
// ---------------------------------------------------------------------------
__global__ __launch_bounds__(256) void cvt_bf16(const float* __restrict__ in,
                                                u16* __restrict__ out, int n8) {
  for (int i = blockIdx.x * blockDim.x + threadIdx.x; i < n8;
       i += gridDim.x * blockDim.x) {
    const float4* p = (const float4*)in + (size_t)i * 2;
    float4 a = p[0], b = p[1];
    s16x8 r;
    r[0] = (short)f2bf(a.x); r[1] = (short)f2bf(a.y);
    r[2] = (short)f2bf(a.z); r[3] = (short)f2bf(a.w);
    r[4] = (short)f2bf(b.x); r[5] = (short)f2bf(b.y);
    r[6] = (short)f2bf(b.z); r[7] = (short)f2bf(b.w);
    *(s16x8*)(out + (size_t)i * 8) = r;
  }
}

// ---------------------------------------------------------------------------
// 256x256-tile GEMM C[M,N] = A[M,1024] * W[N,1024]^T, bf16 in, f32 accum.
// 512 thr = 8 waves (2M x 4N), per-wave 128x64 out = 8x4 frags of 16x16x32.
// T3-minimum double-buffer (catalog-verified recipe): BK=32, 2 LDS buffers
// (64 KiB -> 2 blocks/CU for cross-block overlap of the drain stall, m114),
// one barrier per K-tile:
//   iter t: STAGE(t+1) -> 12 ds_reads buf[t] -> lgkmcnt(0)+sched_barrier ->
//           setprio(1) 32 MFMA setprio(0) -> vmcnt(0) -> barrier
// T2 swizzle (PMC-verified 0 conflicts): phys granule = g ^ ((row>>1)&3);
// linear LDS dest, inverse-swizzled global source, swizzled ds_read granule.
// T1: XCD-chunked block swizzle.
// ---------------------------------------------------------------------------
template <bool QS, bool F32OUT, int GN>
__global__ __launch_bounds__(512, 4) void gemm256(const u16* __restrict__ A,
                                                  const u16* __restrict__ W,
                                                  void* __restrict__ C) {
  __shared__ alignas(16) u16 lds[2 * 16384];  // 2 x (A 16KB + B 16KB)
  const int tid = threadIdx.x;
  const int wv = tid >> 6, lane = tid & 63;
  const int fr = lane & 15, fg = lane >> 4;
  const int wm = wv >> 2, wn = wv & 3;
  const int N = GN * 256;

  // T1: XCD-chunked swizzle (nwg % 8 == 0), bm-major logical order
  const int nwg = 64 * GN;
  const int p = blockIdx.x;
  const int logical = (p & 7) * (nwg >> 3) + (p >> 3);
  const int bm = logical / GN, bn = logical % GN;

  // staging: thread covers (row = tid>>2 [+128], granule tid&3), src inverse-swz
  const int srow = tid >> 2;
  const int skg = (tid & 3) ^ ((tid >> 3) & 3);

  const u16* As = A + (size_t)(bm * 256 + srow) * 1024 + skg * 8;
  const u16* Ws = W + (size_t)(bn * 256 + srow) * 1024 + skg * 8;

  const f32x4 fz = {0.f, 0.f, 0.f, 0.f};
  f32x4 acc[8][4];
#pragma unroll
  for (int i = 0; i < 8; ++i)
#pragma unroll
    for (int j = 0; j < 4; ++j) acc[i][j] = fz;

  auto STAGE = [&](int t) {
    u16* dst = lds + (t & 1) * 16384;
    const int k0 = t * 32;
    gld16(As + k0,          dst + wv * 512);           // A rows 0..127
    gld16(As + 131072 + k0, dst + 4096 + wv * 512);    // A rows 128..255
    gld16(Ws + k0,          dst + 8192 + wv * 512);    // B rows 0..127
    gld16(Ws + 131072 + k0, dst + 12288 + wv * 512);   // B rows 128..255
  };

  STAGE(0);
  asm volatile("s_waitcnt vmcnt(0)" ::: "memory");
  __builtin_amdgcn_s_barrier();

  // swizzled read granule: fg ^ ((fr>>1)&3)
  const int rsw = (fg ^ ((fr >> 1) & 3)) * 8;
  const int aoff = (wm * 128 + fr) * 32 + rsw;
  const int boff = 8192 + (wn * 64 + fr) * 32 + rsw;

  for (int t = 0; t < 32; ++t) {
    const u16* buf = lds + (t & 1) * 16384;
    if (t < 31) STAGE(t + 1);  // into buf^1: all reads of tile t-1 done pre-barrier

    s16x8 af[8], bv[4];
#pragma unroll
    for (int mi = 0; mi < 4; ++mi)
      af[mi] = *(const s16x8*)(buf + aoff + mi * 512);
#pragma unroll
    for (int ni = 0; ni < 4; ++ni)
      bv[ni] = *(const s16x8*)(buf + boff + ni * 512);
#pragma unroll
    for (int mi = 4; mi < 8; ++mi)
      af[mi] = *(const s16x8*)(buf + aoff + mi * 512);

    asm volatile("s_waitcnt lgkmcnt(0)" ::: "memory");
    __builtin_amdgcn_sched_barrier(0);
    __builtin_amdgcn_s_setprio(1);
#pragma unroll
    for (int ni = 0; ni < 4; ++ni)
#pragma unroll
      for (int mi = 0; mi < 8; ++mi)
        acc[mi][ni] = MFMA_BF16(af[mi], bv[ni], acc[mi][ni]);
    __builtin_amdgcn_s_setprio(0);

    if (t < 31) {
      asm volatile("s_waitcnt vmcnt(0)" ::: "memory");  // tile t+1 landed
      __builtin_amdgcn_s_barrier();
    }
  }

  const float scale = (QS && bn < 4) ? 0.125f : 1.0f;
#pragma unroll
  for (int mi = 0; mi < 8; ++mi)
#pragma unroll
    for (int ni = 0; ni < 4; ++ni) {
      const int row = bm * 256 + wm * 128 + mi * 16 + fg * 4;
      const int col = bn * 256 + wn * 64 + ni * 16 + fr;
      if (F32OUT) {
        float* cp = (float*)C + (size_t)row * N + col;
#pragma unroll
        for (int r = 0; r < 4; ++r) cp[(size_t)r * N] = acc[mi][ni][r] * scale;
      } else {
        u16* cp = (u16*)C + (size_t)row * N + col;
#pragma unroll
        for (int r = 0; r < 4; ++r) cp[(size_t)r * N] = f2bf(acc[mi][ni][r] * scale);
      }
    }
}

// ---------------------------------------------------------------------------
// Windowed attention. Grid = 256 blocks, 256 threads (4 waves).
// Block -> (b,h, qb): qb = 64-row slice of the 256 window-rows.
// Per (b,h): Q,K,V are [256 rows][Df=1024]; row w, col d=(p*64+e) lives at
// qkv[(b*4096 + w*16 + p)*3072 + s*1024 + h*64 + e], s in {0,1,2}.
// ---------------------------------------------------------------------------
__global__ __launch_bounds__(256) void attn_win(const u16* __restrict__ qkv,
                                                u16* __restrict__ attn) {
  const int bid = blockIdx.x;
  const int bh = (bid & 7) + ((bid >> 5) << 3);  // same bh -> same XCD (bid%8)
  const int qb = (bid >> 3) & 3;
  const int b = bh >> 4, h = bh & 15;

  const int tid = threadIdx.x;
  const int wv = tid >> 6, lane = tid & 63;
  const int fr = lane & 15, fg = lane >> 4;
  const int li = lane >> 2, lc = lane & 3;

  __shared__ alignas(16) char smem[33792 + 20480];
  u16* lP = (u16*)smem;                      // [64][264] bf16 P (persist ph2->ph3)
  u16* lQ = (u16*)(smem + 33792);            // [64][32]
  u16* lK = (u16*)(smem + 33792 + 4096);     // [256][32]
  float* redm = (float*)(smem + 33792);          // [4][64]
  float* reds = (float*)(smem + 33792 + 1024);   // [4][64]
  u16* lVt = (u16*)(smem + 33792);           // [256 n][40] V^T tile (32 x + pad)

  const size_t qbase = (size_t)b * 4096 * 3072;

  const f32x4 fz = {0.f, 0.f, 0.f, 0.f};
  f32x4 acc[4][4];
#pragma unroll
  for (int i = 0; i < 4; ++i)
#pragma unroll
    for (int j = 0; j < 4; ++j) acc[i][j] = fz;

  // ---- phase 1: S = Q K^T  (wave wv owns cols wv*64..+64, all 64 rows)
  for (int kt = 0; kt < 32; ++kt) {
    const size_t dofs = (size_t)(kt >> 1) * 3072 + h * 64 + (kt & 1) * 32 + lc * 8;
    {
      const int r = wv * 16 + li;  // q-row 0..63
      gld16(qkv + qbase + (size_t)((qb * 64 + r) * 16) * 3072 + dofs, lQ + wv * 512);
    }
#pragma unroll
    for (int j = 0; j < 4; ++j) {
      const int q = wv * 4 + j;
      const int r = q * 16 + li;  // k-row 0..255
      gld16(qkv + qbase + (size_t)(r * 16) * 3072 + 1024 + dofs, lK + q * 512);
    }
    __syncthreads();
    s16x8 qa[4];
#pragma unroll
    for (int mi = 0; mi < 4; ++mi)
      qa[mi] = *(const s16x8*)(lQ + (mi * 16 + fr) * 32 + fg * 8);
#pragma unroll
    for (int ni = 0; ni < 4; ++ni) {
      s16x8 kb = *(const s16x8*)(lK + (wv * 64 + ni * 16 + fr) * 32 + fg * 8);
#pragma unroll
      for (int mi = 0; mi < 4; ++mi)
        acc[mi][ni] = MFMA_BF16(qa[mi], kb, acc[mi][ni]);
    }
    __syncthreads();
  }

  // ---- phase 2: softmax over 256 cols; rows per lane: mi*16 + fg*4 + r
  float rmax[4][4], rnrm[4][4];
#pragma unroll
  for (int mi = 0; mi < 4; ++mi)
#pragma unroll
    for (int r = 0; r < 4; ++r) {
      float m = fmaxf(fmaxf(acc[mi][0][r], acc[mi][1][r]),
                      fmaxf(acc[mi][2][r], acc[mi][3][r]));
      for (int o = 1; o < 16; o <<= 1) m = fmaxf(m, __shfl_xor(m, o));
      rmax[mi][r] = m;
    }
  if (fr == 0) {
#pragma unroll
    for (int mi = 0; mi < 4; ++mi)
#pragma unroll
      for (int r = 0; r < 4; ++r) redm[wv * 64 + mi * 16 + fg * 4 + r] = rmax[mi][r];
  }
  __syncthreads();
#pragma unroll
  for (int mi = 0; mi < 4; ++mi)
#pragma unroll
    for (int r = 0; r < 4; ++r) {
      const int row = mi * 16 + fg * 4 + r;
      rmax[mi][r] = fmaxf(fmaxf(redm[row], redm[64 + row]),
                          fmaxf(redm[128 + row], redm[192 + row]));
    }
#pragma unroll
  for (int mi = 0; mi < 4; ++mi)
#pragma unroll
    for (int r = 0; r < 4; ++r) {
      float s = 0.f;
#pragma unroll
      for (int ni = 0; ni < 4; ++ni) {
        float p = exp2f((acc[mi][ni][r] - rmax[mi][r]) * 1.4426950408889634f);
        acc[mi][ni][r] = p;
        s += p;
      }
      for (int o = 1; o < 16; o <<= 1) s += __shfl_xor(s, o);
      rnrm[mi][r] = s;
    }
  if (fr == 0) {
#pragma unroll
    for (int mi = 0; mi < 4; ++mi)
#pragma unroll
      for (int r = 0; r < 4; ++r) reds[wv * 64 + mi * 16 + fg * 4 + r] = rnrm[mi][r];
  }
  __syncthreads();
#pragma unroll
  for (int mi = 0; mi < 4; ++mi)
#pragma unroll
    for (int r = 0; r < 4; ++r) {
      const int row = mi * 16 + fg * 4 + r;
      rnrm[mi][r] = 1.f / (reds[row] + reds[64 + row] + reds[128 + row] + reds[192 + row]);
    }
#pragma unroll
  for (int mi = 0; mi < 4; ++mi)
#pragma unroll
    for (int ni = 0; ni < 4; ++ni)
#pragma unroll
      for (int r = 0; r < 4; ++r)
        lP[(mi * 16 + fg * 4 + r) * 264 + wv * 64 + ni * 16 + fr] =
            f2bf(acc[mi][ni][r] * rnrm[mi][r]);
  __syncthreads();  // lP ready; redm/reds region freed for lVt

  // ---- phase 3: O = P V, n-chunks of 256 cols, k(x)-tiles of 32
#pragma unroll 1
  for (int nc = 0; nc < 4; ++nc) {
    f32x4 oacc[4][4];
#pragma unroll
    for (int i = 0; i < 4; ++i)
#pragma unroll
      for (int j = 0; j < 4; ++j) oacc[i][j] = fz;
#pragma unroll 1
    for (int xt = 0; xt < 8; ++xt) {
      // stage V^T tile: [32 x][256 n] -> lVt[n][40] (x at 0..31, pad to 40)
#pragma unroll
      for (int it = 0; it < 4; ++it) {
        const int id = it * 256 + tid;
        const int xl = id & 31, ng = id >> 5;
        const int d = nc * 256 + ng * 8;
        const u16* g = qkv + qbase +
                       (size_t)((xt * 32 + xl) * 16 + (d >> 6)) * 3072 + 2048 +
                       h * 64 + (d & 63);
        s16x8 v = *(const s16x8*)g;
#pragma unroll
        for (int i = 0; i < 8; ++i) lVt[(ng * 8 + i) * 40 + xl] = (u16)v[i];
      }
      __syncthreads();
      s16x8 pa[4];
#pragma unroll
      for (int mi = 0; mi < 4; ++mi)
        pa[mi] = *(const s16x8*)(lP + (mi * 16 + fr) * 264 + xt * 32 + fg * 8);
#pragma unroll
      for (int ni = 0; ni < 4; ++ni) {
        s16x8 vb = *(const s16x8*)(lVt + (wv * 64 + ni * 16 + fr) * 40 + fg * 8);
#pragma unroll
        for (int mi = 0; mi < 4; ++mi)
          oacc[mi][ni] = MFMA_BF16(pa[mi], vb, oacc[mi][ni]);
      }
      __syncthreads();
    }
    // store O chunk -> attn_out token layout [B,N,H*hd]
#pragma unroll
    for (int mi = 0; mi < 4; ++mi)
#pragma unroll
      for (int ni = 0; ni < 4; ++ni) {
        const int row = mi * 16 + fg * 4;
        const int d = nc * 256 + wv * 64 + ni * 16 + fr;
        const int p = d >> 6, e = d & 63;
        const size_t base =
            (size_t)(b * 4096 + (qb * 64 + row) * 16 + p) * 1024 + h * 64 + e;
#pragma unroll
        for (int r = 0; r < 4; ++r)
          attn[base + (size_t)r * 16 * 1024] = f2bf(oacc[mi][ni][r]);
      }
  }
}

// ---------------------------------------------------------------------------
extern "C" void kernel_launch(void* const* d_in, const int* in_sizes, int n_in,
                              void* d_out, int out_size, void* d_ws, size_t ws_size,
                              hipStream_t stream) {
  (void)in_sizes; (void)n_in; (void)out_size; (void)ws_size;
  const float* x = (const float*)d_in[0];      // [16384,1024] f32
  const float* wqkv = (const float*)d_in[1];   // [3072,1024] f32
  const float* wproj = (const float*)d_in[2];  // [1024,1024] f32
  float* out = (float*)d_out;                  // [16384,1024] f32

  char* ws = (char*)d_ws;
  u16* qkv = (u16*)ws;                          // [16384,3072] bf16 (100.7 MB)
  u16* xbf = (u16*)(ws + 100663296);            // [16384,1024] bf16 (33.6 MB)
  u16* attn = xbf;                              // reuse: xbf dead after gemm1
  u16* wqkvb = (u16*)(ws + 134217728);          // [3072,1024] bf16 (6.3 MB)
  u16* wprojb = (u16*)(ws + 140509184);         // [1024,1024] bf16 (2.1 MB)

  cvt_bf16<<<2048, 256, 0, stream>>>(x, xbf, 16777216 / 8);
  cvt_bf16<<<1536, 256, 0, stream>>>(wqkv, wqkvb, 3145728 / 8);
  cvt_bf16<<<512, 256, 0, stream>>>(wproj, wprojb, 1048576 / 8);

  gemm256<true, false, 12><<<768, 512, 0, stream>>>(xbf, wqkvb, qkv);
  attn_win<<<256, 256, 0, stream>>>(qkv, attn);
  gemm256<false, true, 4><<<256, 512, 0, stream>>>(attn, wprojb, out);
}

// Round 6
// 244.007 us; speedup vs baseline: 6.1218x; 6.1218x over previous
//
#include <hip/hip_runtime.h>
#include <hip/hip_bf16.h>
#include <stdint.h>

// SlidingWindowAttention: x[4,4096,1024] f32, Wqkv[3072,1024] f32, Wproj[1024,1024] f32
// I/O f32; internal bf16 (MFMA) with f32 accum.
// qkv = x@Wqkv^T (q*=0.125 fused) -> per (b,h) flattened-window attention
// (256x256 over Df=1024) -> out = attn_out @ Wproj^T (f32 out).

using u16 = unsigned short;
typedef __attribute__((ext_vector_type(4))) float f32x4;
typedef __attribute__((ext_vector_type(8))) short s16x8;

#define MFMA_BF16(a, b, c) __builtin_amdgcn_mfma_f32_16x16x32_bf16((a), (b), (c), 0, 0, 0)

__device__ __forceinline__ u16 f2bf(float f) {
  union { float f; uint32_t u; } v; v.f = f;
  uint32_t r = v.u + 0x7fffu + ((v.u >> 16) & 1u);  // RNE
  return (u16)(r >> 16);
}

// async global->LDS, 16B per lane; LDS dest is wave-uniform base + lane*16
__device__ __forceinline__ void gld16(const void* g, void* l) {
  auto gp = (const __attribute__((address_space(1))) void*)(uintptr_t)g;
  auto lp = (__attribute__((address_space(3))) void*)(uint32_t)(uintptr_t)l;
  __builtin_amdgcn_global_load_lds(gp, lp, 16, 0, 0);
}

// ---------------------------------------------------------------------------
// f32 -> bf16 convert, 8 elems/thread/iter (32B in, 16B out)
// ---------------------------------------------------------------------------
__global__ __launch_bounds__(256) void cvt_bf16(const float* __restrict__ in,
                                                u16* __restrict__ out, int n8) {
  for (int i = blockIdx.x * blockDim.x + threadIdx.x; i < n8;
       i += gridDim.x * blockDim.x) {
    const float4* p = (const float4*)in + (size_t)i * 2;
    float4 a = p[0], b = p[1];
    s16x8 r;
    r[0] = (short)f2bf(a.x); r[1] = (short)f2bf(a.y);
    r[2] = (short)f2bf(a.z); r[3] = (short)f2bf(a.w);
    r[4] = (short)f2bf(b.x); r[5] = (short)f2bf(b.y);
    r[6] = (short)f2bf(b.z); r[7] = (short)f2bf(b.w);
    *(s16x8*)(out + (size_t)i * 8) = r;
  }
}

// ---------------------------------------------------------------------------
// 256x256-tile GEMM C[M,N] = A[M,1024] * W[N,1024]^T, bf16 in, f32 accum.
// 512 thr = 8 waves (2M x 4N), per-wave 128x64 out = 8x4 frags of 16x16x32.
// Fine-phase schedule derived as a conservative delta from the round-3
// verified skeleton: same 3-buffer ring (96 KiB), same STAGE addressing,
// reads only delayed within the same stability window, barriers only added.
// Per K-tile t, two windows:
//  W1: STAGE_A(t+2); vmcnt(6|4|0); bar; read a0x4,bv x4; lgkm0+SGB;
//      setprio 16 MFMA(mi0-3); bar
//  W2: read a1x4; STAGE_B(t+2); lgkm0+SGB; setprio 16 MFMA(mi4-7); bar
// vmcnt ledger (2 instrs per STAGE half): outstanding at iter-t top =
// {B(t),A(t+1),B(t+1),A(t+2)} <= 8 -> vmcnt(6) retires B(t) => tile t landed.
// Drain: t=30 vmcnt(4), t=31 vmcnt(0). In-flight writes never target the
// buffer being read (targets (t+1)%3,(t+2)%3 only).
// T2 swizzle (PMC-verified 0 conflicts): phys granule = g ^ ((row>>1)&3);
// linear LDS dest, inverse-swizzled global source, swizzled ds_read granule.
// T1: XCD-chunked block swizzle.
// ---------------------------------------------------------------------------
template <bool QS, bool F32OUT, int GN>
__global__ __launch_bounds__(512, 2) void gemm256(const u16* __restrict__ A,
                                                  const u16* __restrict__ W,
                                                  void* __restrict__ C) {
  __shared__ alignas(16) u16 lds[3 * 16384];  // 3 x (A 16KB + B 16KB)
  const int tid = threadIdx.x;
  const int wv = tid >> 6, lane = tid & 63;
  const int fr = lane & 15, fg = lane >> 4;
  const int wm = wv >> 2, wn = wv & 3;
  const int N = GN * 256;

  // T1: XCD-chunked swizzle (nwg % 8 == 0), bm-major logical order
  const int nwg = 64 * GN;
  const int p = blockIdx.x;
  const int logical = (p & 7) * (nwg >> 3) + (p >> 3);
  const int bm = logical / GN, bn = logical % GN;

  // staging: thread covers (row = tid>>2 [+128], granule tid&3), src inverse-swz
  const int srow = tid >> 2;
  const int skg = (tid & 3) ^ ((tid >> 3) & 3);

  const u16* As = A + (size_t)(bm * 256 + srow) * 1024 + skg * 8;
  const u16* Ws = W + (size_t)(bn * 256 + srow) * 1024 + skg * 8;

  const f32x4 fz = {0.f, 0.f, 0.f, 0.f};
  f32x4 acc[8][4];
#pragma unroll
  for (int i = 0; i < 8; ++i)
#pragma unroll
    for (int j = 0; j < 4; ++j) acc[i][j] = fz;

  auto STAGE_A = [&](int t) {
    u16* dst = lds + (t % 3) * 16384;
    const int k0 = t * 32;
    gld16(As + k0,          dst + wv * 512);           // A rows 0..127
    gld16(As + 131072 + k0, dst + 4096 + wv * 512);    // A rows 128..255
  };
  auto STAGE_B = [&](int t) {
    u16* dst = lds + (t % 3) * 16384;
    const int k0 = t * 32;
    gld16(Ws + k0,          dst + 8192 + wv * 512);    // B rows 0..127
    gld16(Ws + 131072 + k0, dst + 12288 + wv * 512);   // B rows 128..255
  };

  // prologue: tiles 0 and 1 fully issued
  STAGE_A(0); STAGE_B(0);
  STAGE_A(1); STAGE_B(1);

  // swizzled read granule: fg ^ ((fr>>1)&3)
  const int rsw = (fg ^ ((fr >> 1) & 3)) * 8;
  const int aoff = (wm * 128 + fr) * 32 + rsw;
  const int boff = 8192 + (wn * 64 + fr) * 32 + rsw;

  for (int t = 0; t < 32; ++t) {
    const u16* buf = lds + (t % 3) * 16384;

    // ---- window 1 ----
    if (t < 30) {
      STAGE_A(t + 2);
      asm volatile("s_waitcnt vmcnt(6)" ::: "memory");  // tile t landed
    } else if (t == 30) {
      asm volatile("s_waitcnt vmcnt(4)" ::: "memory");  // tile 30 landed
    } else {
      asm volatile("s_waitcnt vmcnt(0)" ::: "memory");  // tile 31 landed
    }
    __builtin_amdgcn_s_barrier();  // all waves' tile-t data visible

    s16x8 a0[4], a1[4], bv[4];
#pragma unroll
    for (int mi = 0; mi < 4; ++mi)
      a0[mi] = *(const s16x8*)(buf + aoff + mi * 512);
#pragma unroll
    for (int ni = 0; ni < 4; ++ni)
      bv[ni] = *(const s16x8*)(buf + boff + ni * 512);

    asm volatile("s_waitcnt lgkmcnt(0)" ::: "memory");
    __builtin_amdgcn_sched_barrier(0);
    __builtin_amdgcn_s_setprio(1);
#pragma unroll
    for (int ni = 0; ni < 4; ++ni)
#pragma unroll
      for (int mi = 0; mi < 4; ++mi)
        acc[mi][ni] = MFMA_BF16(a0[mi], bv[ni], acc[mi][ni]);
    __builtin_amdgcn_s_setprio(0);
    __builtin_amdgcn_s_barrier();

    // ---- window 2 ----
#pragma unroll
    for (int mi = 0; mi < 4; ++mi)
      a1[mi] = *(const s16x8*)(buf + aoff + (4 + mi) * 512);
    if (t < 30) STAGE_B(t + 2);

    asm volatile("s_waitcnt lgkmcnt(0)" ::: "memory");
    __builtin_amdgcn_sched_barrier(0);
    __builtin_amdgcn_s_setprio(1);
#pragma unroll
    for (int ni = 0; ni < 4; ++ni)
#pragma unroll
      for (int mi = 0; mi < 4; ++mi)
        acc[4 + mi][ni] = MFMA_BF16(a1[mi], bv[ni], acc[4 + mi][ni]);
    __builtin_amdgcn_s_setprio(0);
    __builtin_amdgcn_s_barrier();  // all reads of buf t done
  }

  const float scale = (QS && bn < 4) ? 0.125f : 1.0f;
#pragma unroll
  for (int mi = 0; mi < 8; ++mi)
#pragma unroll
    for (int ni = 0; ni < 4; ++ni) {
      const int row = bm * 256 + wm * 128 + mi * 16 + fg * 4;
      const int col = bn * 256 + wn * 64 + ni * 16 + fr;
      if (F32OUT) {
        float* cp = (float*)C + (size_t)row * N + col;
#pragma unroll
        for (int r = 0; r < 4; ++r) cp[(size_t)r * N] = acc[mi][ni][r] * scale;
      } else {
        u16* cp = (u16*)C + (size_t)row * N + col;
#pragma unroll
        for (int r = 0; r < 4; ++r) cp[(size_t)r * N] = f2bf(acc[mi][ni][r] * scale);
      }
    }
}

// ---------------------------------------------------------------------------
// Windowed attention. Grid = 256 blocks, 256 threads (4 waves).
// Block -> (b,h, qb): qb = 64-row slice of the 256 window-rows.
// Per (b,h): Q,K,V are [256 rows][Df=1024]; row w, col d=(p*64+e) lives at
// qkv[(b*4096 + w*16 + p)*3072 + s*1024 + h*64 + e], s in {0,1,2}.
// ---------------------------------------------------------------------------
__global__ __launch_bounds__(256) void attn_win(const u16* __restrict__ qkv,
                                                u16* __restrict__ attn) {
  const int bid = blockIdx.x;
  const int bh = (bid & 7) + ((bid >> 5) << 3);  // same bh -> same XCD (bid%8)
  const int qb = (bid >> 3) & 3;
  const int b = bh >> 4, h = bh & 15;

  const int tid = threadIdx.x;
  const int wv = tid >> 6, lane = tid & 63;
  const int fr = lane & 15, fg = lane >> 4;
  const int li = lane >> 2, lc = lane & 3;

  __shared__ alignas(16) char smem[33792 + 20480];
  u16* lP = (u16*)smem;                      // [64][264] bf16 P (persist ph2->ph3)
  u16* lQ = (u16*)(smem + 33792);            // [64][32]
  u16* lK = (u16*)(smem + 33792 + 4096);     // [256][32]
  float* redm = (float*)(smem + 33792);          // [4][64]
  float* reds = (float*)(smem + 33792 + 1024);   // [4][64]
  u16* lVt = (u16*)(smem + 33792);           // [256 n][40] V^T tile (32 x + pad)

  const size_t qbase = (size_t)b * 4096 * 3072;

  const f32x4 fz = {0.f, 0.f, 0.f, 0.f};
  f32x4 acc[4][4];
#pragma unroll
  for (int i = 0; i < 4; ++i)
#pragma unroll
    for (int j = 0; j < 4; ++j) acc[i][j] = fz;

  // ---- phase 1: S = Q K^T  (wave wv owns cols wv*64..+64, all 64 rows)
  for (int kt = 0; kt < 32; ++kt) {
    const size_t dofs = (size_t)(kt >> 1) * 3072 + h * 64 + (kt & 1) * 32 + lc * 8;
    {
      const int r = wv * 16 + li;  // q-row 0..63
      gld16(qkv + qbase + (size_t)((qb * 64 + r) * 16) * 3072 + dofs, lQ + wv * 512);
    }
#pragma unroll
    for (int j = 0; j < 4; ++j) {
      const int q = wv * 4 + j;
      const int r = q * 16 + li;  // k-row 0..255
      gld16(qkv + qbase + (size_t)(r * 16) * 3072 + 1024 + dofs, lK + q * 512);
    }
    __syncthreads();
    s16x8 qa[4];
#pragma unroll
    for (int mi = 0; mi < 4; ++mi)
      qa[mi] = *(const s16x8*)(lQ + (mi * 16 + fr) * 32 + fg * 8);
#pragma unroll
    for (int ni = 0; ni < 4; ++ni) {
      s16x8 kb = *(const s16x8*)(lK + (wv * 64 + ni * 16 + fr) * 32 + fg * 8);
#pragma unroll
      for (int mi = 0; mi < 4; ++mi)
        acc[mi][ni] = MFMA_BF16(qa[mi], kb, acc[mi][ni]);
    }
    __syncthreads();
  }

  // ---- phase 2: softmax over 256 cols; rows per lane: mi*16 + fg*4 + r
  float rmax[4][4], rnrm[4][4];
#pragma unroll
  for (int mi = 0; mi < 4; ++mi)
#pragma unroll
    for (int r = 0; r < 4; ++r) {
      float m = fmaxf(fmaxf(acc[mi][0][r], acc[mi][1][r]),
                      fmaxf(acc[mi][2][r], acc[mi][3][r]));
      for (int o = 1; o < 16; o <<= 1) m = fmaxf(m, __shfl_xor(m, o));
      rmax[mi][r] = m;
    }
  if (fr == 0) {
#pragma unroll
    for (int mi = 0; mi < 4; ++mi)
#pragma unroll
      for (int r = 0; r < 4; ++r) redm[wv * 64 + mi * 16 + fg * 4 + r] = rmax[mi][r];
  }
  __syncthreads();
#pragma unroll
  for (int mi = 0; mi < 4; ++mi)
#pragma unroll
    for (int r = 0; r < 4; ++r) {
      const int row = mi * 16 + fg * 4 + r;
      rmax[mi][r] = fmaxf(fmaxf(redm[row], redm[64 + row]),
                          fmaxf(redm[128 + row], redm[192 + row]));
    }
#pragma unroll
  for (int mi = 0; mi < 4; ++mi)
#pragma unroll
    for (int r = 0; r < 4; ++r) {
      float s = 0.f;
#pragma unroll
      for (int ni = 0; ni < 4; ++ni) {
        float p = exp2f((acc[mi][ni][r] - rmax[mi][r]) * 1.4426950408889634f);
        acc[mi][ni][r] = p;
        s += p;
      }
      for (int o = 1; o < 16; o <<= 1) s += __shfl_xor(s, o);
      rnrm[mi][r] = s;
    }
  if (fr == 0) {
#pragma unroll
    for (int mi = 0; mi < 4; ++mi)
#pragma unroll
      for (int r = 0; r < 4; ++r) reds[wv * 64 + mi * 16 + fg * 4 + r] = rnrm[mi][r];
  }
  __syncthreads();
#pragma unroll
  for (int mi = 0; mi < 4; ++mi)
#pragma unroll
    for (int r = 0; r < 4; ++r) {
      const int row = mi * 16 + fg * 4 + r;
      rnrm[mi][r] = 1.f / (reds[row] + reds[64 + row] + reds[128 + row] + reds[192 + row]);
    }
#pragma unroll
  for (int mi = 0; mi < 4; ++mi)
#pragma unroll
    for (int ni = 0; ni < 4; ++ni)
#pragma unroll
      for (int r = 0; r < 4; ++r)
        lP[(mi * 16 + fg * 4 + r) * 264 + wv * 64 + ni * 16 + fr] =
            f2bf(acc[mi][ni][r] * rnrm[mi][r]);
  __syncthreads();  // lP ready; redm/reds region freed for lVt

  // ---- phase 3: O = P V, n-chunks of 256 cols, k(x)-tiles of 32
#pragma unroll 1
  for (int nc = 0; nc < 4; ++nc) {
    f32x4 oacc[4][4];
#pragma unroll
    for (int i = 0; i < 4; ++i)
#pragma unroll
      for (int j = 0; j < 4; ++j) oacc[i][j] = fz;
#pragma unroll 1
    for (int xt = 0; xt < 8; ++xt) {
      // stage V^T tile: [32 x][256 n] -> lVt[n][40] (x at 0..31, pad to 40)
#pragma unroll
      for (int it = 0; it < 4; ++it) {
        const int id = it * 256 + tid;
        const int xl = id & 31, ng = id >> 5;
        const int d = nc * 256 + ng * 8;
        const u16* g = qkv + qbase +
                       (size_t)((xt * 32 + xl) * 16 + (d >> 6)) * 3072 + 2048 +
                       h * 64 + (d & 63);
        s16x8 v = *(const s16x8*)g;
#pragma unroll
        for (int i = 0; i < 8; ++i) lVt[(ng * 8 + i) * 40 + xl] = (u16)v[i];
      }
      __syncthreads();
      s16x8 pa[4];
#pragma unroll
      for (int mi = 0; mi < 4; ++mi)
        pa[mi] = *(const s16x8*)(lP + (mi * 16 + fr) * 264 + xt * 32 + fg * 8);
#pragma unroll
      for (int ni = 0; ni < 4; ++ni) {
        s16x8 vb = *(const s16x8*)(lVt + (wv * 64 + ni * 16 + fr) * 40 + fg * 8);
#pragma unroll
        for (int mi = 0; mi < 4; ++mi)
          oacc[mi][ni] = MFMA_BF16(pa[mi], vb, oacc[mi][ni]);
      }
      __syncthreads();
    }
    // store O chunk -> attn_out token layout [B,N,H*hd]
#pragma unroll
    for (int mi = 0; mi < 4; ++mi)
#pragma unroll
      for (int ni = 0; ni < 4; ++ni) {
        const int row = mi * 16 + fg * 4;
        const int d = nc * 256 + wv * 64 + ni * 16 + fr;
        const int p = d >> 6, e = d & 63;
        const size_t base =
            (size_t)(b * 4096 + (qb * 64 + row) * 16 + p) * 1024 + h * 64 + e;
#pragma unroll
        for (int r = 0; r < 4; ++r)
          attn[base + (size_t)r * 16 * 1024] = f2bf(oacc[mi][ni][r]);
      }
  }
}

// ---------------------------------------------------------------------------
extern "C" void kernel_launch(void* const* d_in, const int* in_sizes, int n_in,
                              void* d_out, int out_size, void* d_ws, size_t ws_size,
                              hipStream_t stream) {
  (void)in_sizes; (void)n_in; (void)out_size; (void)ws_size;
  const float* x = (const float*)d_in[0];      // [16384,1024] f32
  const float* wqkv = (const float*)d_in[1];   // [3072,1024] f32
  const float* wproj = (const float*)d_in[2];  // [1024,1024] f32
  float* out = (float*)d_out;                  // [16384,1024] f32

  char* ws = (char*)d_ws;
  u16* qkv = (u16*)ws;                          // [16384,3072] bf16 (100.7 MB)
  u16* xbf = (u16*)(ws + 100663296);            // [16384,1024] bf16 (33.6 MB)
  u16* attn = xbf;                              // reuse: xbf dead after gemm1
  u16* wqkvb = (u16*)(ws + 134217728);          // [3072,1024] bf16 (6.3 MB)
  u16* wprojb = (u16*)(ws + 140509184);         // [1024,1024] bf16 (2.1 MB)

  cvt_bf16<<<2048, 256, 0, stream>>>(x, xbf, 16777216 / 8);
  cvt_bf16<<<1536, 256, 0, stream>>>(wqkv, wqkvb, 3145728 / 8);
  cvt_bf16<<<512, 256, 0, stream>>>(wproj, wprojb, 1048576 / 8);

  gemm256<true, false, 12><<<768, 512, 0, stream>>>(xbf, wqkvb, qkv);
  attn_win<<<256, 256, 0, stream>>>(qkv, attn);
  gemm256<false, true, 4><<<256, 512, 0, stream>>>(attn, wprojb, out);
}

// Round 7
// 239.599 us; speedup vs baseline: 6.2344x; 1.0184x over previous
//
#include <hip/hip_runtime.h>
#include <hip/hip_bf16.h>
#include <stdint.h>

// SlidingWindowAttention: x[4,4096,1024] f32, Wqkv[3072,1024] f32, Wproj[1024,1024] f32
// I/O f32; internal bf16 (MFMA) with f32 accum.
// qkv = x@Wqkv^T (q*=0.125 fused) -> per (b,h) flattened-window attention
// (256x256 over Df=1024) -> out = attn_out @ Wproj^T (f32 out).

using u16 = unsigned short;
typedef __attribute__((ext_vector_type(4))) float f32x4;
typedef __attribute__((ext_vector_type(8))) short s16x8;

#define MFMA_BF16(a, b, c) __builtin_amdgcn_mfma_f32_16x16x32_bf16((a), (b), (c), 0, 0, 0)

__device__ __forceinline__ u16 f2bf(float f) {
  union { float f; uint32_t u; } v; v.f = f;
  uint32_t r = v.u + 0x7fffu + ((v.u >> 16) & 1u);  // RNE
  return (u16)(r >> 16);
}

// async global->LDS, 16B per lane; LDS dest is wave-uniform base + lane*16
__device__ __forceinline__ void gld16(const void* g, void* l) {
  auto gp = (const __attribute__((address_space(1))) void*)(uintptr_t)g;
  auto lp = (__attribute__((address_space(3))) void*)(uint32_t)(uintptr_t)l;
  __builtin_amdgcn_global_load_lds(gp, lp, 16, 0, 0);
}

// ---------------------------------------------------------------------------
// f32 -> bf16 convert, 8 elems/thread/iter (32B in, 16B out)
// ---------------------------------------------------------------------------
__global__ __launch_bounds__(256) void cvt_bf16(const float* __restrict__ in,
                                                u16* __restrict__ out, int n8) {
  for (int i = blockIdx.x * blockDim.x + threadIdx.x; i < n8;
       i += gridDim.x * blockDim.x) {
    const float4* p = (const float4*)in + (size_t)i * 2;
    float4 a = p[0], b = p[1];
    s16x8 r;
    r[0] = (short)f2bf(a.x); r[1] = (short)f2bf(a.y);
    r[2] = (short)f2bf(a.z); r[3] = (short)f2bf(a.w);
    r[4] = (short)f2bf(b.x); r[5] = (short)f2bf(b.y);
    r[6] = (short)f2bf(b.z); r[7] = (short)f2bf(b.w);
    *(s16x8*)(out + (size_t)i * 8) = r;
  }
}

// ---------------------------------------------------------------------------
// 256x256-tile GEMM C[M,N] = A[M,1024] * W[N,1024]^T, bf16 in, f32 accum.
// 512 thr = 8 waves (2M x 4N), per-wave 128x64 out = 8x4 frags of 16x16x32.
// Hoisted-read pipeline (delta from r6-verified skeleton): all 12 ds_reads of
// tile t issued at TOP of iter t (buf t stable: landed + visible since iter
// t-1's W1 barrier); staggered counted waits lgkmcnt(4)/lgkmcnt(0) so read
// latency hides under barrier-wait + MFMA. 4-buffer ring (128 KiB), stage
// t+3, vmcnt(6) steady = retires through B(t+1) (tile t+1 landed for next
// top-of-iter reads) with A(t+2),B(t+2),A(t+3) in flight; drain 4 -> 0.
// Overwrite ledger: STAGE_{A,B}(t+3) -> buf (t-1)&3; its 12 reads completed
// at lgkmcnt(0)@iter t-1 BEFORE that iter's end-barrier; stages issue after.
// 2 barriers per K-tile. C2 cluster after end-barrier (register-only).
// lgkm counts split-robust: issue order pinned [a0-3,bv][a4-7] via
// sched_barrier; in-order ds retirement => any b128->b64 split stays safe.
// T2 swizzle (PMC-verified 0 conflicts) + T1 XCD chunk swizzle as before.
// ---------------------------------------------------------------------------
template <bool QS, bool F32OUT, int GN>
__global__ __launch_bounds__(512, 2) void gemm256(const u16* __restrict__ A,
                                                  const u16* __restrict__ W,
                                                  void* __restrict__ C) {
  __shared__ alignas(16) u16 lds[4 * 16384];  // 4 x (A 16KB + B 16KB)
  const int tid = threadIdx.x;
  const int wv = tid >> 6, lane = tid & 63;
  const int fr = lane & 15, fg = lane >> 4;
  const int wm = wv >> 2, wn = wv & 3;
  const int N = GN * 256;

  // T1: XCD-chunked swizzle (nwg % 8 == 0), bm-major logical order
  const int nwg = 64 * GN;
  const int p = blockIdx.x;
  const int logical = (p & 7) * (nwg >> 3) + (p >> 3);
  const int bm = logical / GN, bn = logical % GN;

  // staging: thread covers (row = tid>>2 [+128], granule tid&3), src inverse-swz
  const int srow = tid >> 2;
  const int skg = (tid & 3) ^ ((tid >> 3) & 3);

  const u16* As = A + (size_t)(bm * 256 + srow) * 1024 + skg * 8;
  const u16* Ws = W + (size_t)(bn * 256 + srow) * 1024 + skg * 8;

  const f32x4 fz = {0.f, 0.f, 0.f, 0.f};
  f32x4 acc[8][4];
#pragma unroll
  for (int i = 0; i < 8; ++i)
#pragma unroll
    for (int j = 0; j < 4; ++j) acc[i][j] = fz;

  auto STAGE_A = [&](int t) {
    u16* dst = lds + (t & 3) * 16384;
    const int k0 = t * 32;
    gld16(As + k0,          dst + wv * 512);           // A rows 0..127
    gld16(As + 131072 + k0, dst + 4096 + wv * 512);    // A rows 128..255
  };
  auto STAGE_B = [&](int t) {
    u16* dst = lds + (t & 3) * 16384;
    const int k0 = t * 32;
    gld16(Ws + k0,          dst + 8192 + wv * 512);    // B rows 0..127
    gld16(Ws + 131072 + k0, dst + 12288 + wv * 512);   // B rows 128..255
  };

  // prologue: tiles 0,1,2 fully issued; gate tile 0 (outstanding A1B1A2B2 = 8)
  STAGE_A(0); STAGE_B(0);
  STAGE_A(1); STAGE_B(1);
  STAGE_A(2); STAGE_B(2);
  asm volatile("s_waitcnt vmcnt(8)" ::: "memory");
  __builtin_amdgcn_s_barrier();

  // swizzled read granule: fg ^ ((fr>>1)&3)
  const int rsw = (fg ^ ((fr >> 1) & 3)) * 8;
  const int aoff = (wm * 128 + fr) * 32 + rsw;
  const int boff = 8192 + (wn * 64 + fr) * 32 + rsw;

  for (int t = 0; t < 32; ++t) {
    const u16* buf = lds + (t & 3) * 16384;
    s16x8 a0[4], a1[4], bv[4];

    // top-of-iter: all 12 reads of tile t, order pinned [a0,bv][a1]
#pragma unroll
    for (int mi = 0; mi < 4; ++mi)
      a0[mi] = *(const s16x8*)(buf + aoff + mi * 512);
#pragma unroll
    for (int ni = 0; ni < 4; ++ni)
      bv[ni] = *(const s16x8*)(buf + boff + ni * 512);
    __builtin_amdgcn_sched_barrier(0);  // pin issue order for counted lgkm
#pragma unroll
    for (int mi = 0; mi < 4; ++mi)
      a1[mi] = *(const s16x8*)(buf + aoff + (4 + mi) * 512);

    if (t <= 28) {
      STAGE_A(t + 3);
      asm volatile("s_waitcnt vmcnt(6)" ::: "memory");  // tile t+1 landed
    } else if (t == 29) {
      asm volatile("s_waitcnt vmcnt(4)" ::: "memory");  // tile 30 landed
    } else {
      asm volatile("s_waitcnt vmcnt(0)" ::: "memory");  // tile 31 landed
    }
    __builtin_amdgcn_s_barrier();  // tile t+1 visible to all waves

    asm volatile("s_waitcnt lgkmcnt(4)" ::: "memory");  // a0,bv done; a1 may fly
    __builtin_amdgcn_sched_barrier(0);
    __builtin_amdgcn_s_setprio(1);
#pragma unroll
    for (int ni = 0; ni < 4; ++ni)
#pragma unroll
      for (int mi = 0; mi < 4; ++mi)
        acc[mi][ni] = MFMA_BF16(a0[mi], bv[ni], acc[mi][ni]);
    __builtin_amdgcn_s_setprio(0);

    if (t <= 28) STAGE_B(t + 3);
    asm volatile("s_waitcnt lgkmcnt(0)" ::: "memory");  // a1 done
    __builtin_amdgcn_sched_barrier(0);
    __builtin_amdgcn_s_barrier();  // all waves' reads of buf (t-1)-ring done

    __builtin_amdgcn_s_setprio(1);
#pragma unroll
    for (int ni = 0; ni < 4; ++ni)
#pragma unroll
      for (int mi = 0; mi < 4; ++mi)
        acc[4 + mi][ni] = MFMA_BF16(a1[mi], bv[ni], acc[4 + mi][ni]);
    __builtin_amdgcn_s_setprio(0);
  }

  const float scale = (QS && bn < 4) ? 0.125f : 1.0f;
#pragma unroll
  for (int mi = 0; mi < 8; ++mi)
#pragma unroll
    for (int ni = 0; ni < 4; ++ni) {
      const int row = bm * 256 + wm * 128 + mi * 16 + fg * 4;
      const int col = bn * 256 + wn * 64 + ni * 16 + fr;
      if (F32OUT) {
        float* cp = (float*)C + (size_t)row * N + col;
#pragma unroll
        for (int r = 0; r < 4; ++r) cp[(size_t)r * N] = acc[mi][ni][r] * scale;
      } else {
        u16* cp = (u16*)C + (size_t)row * N + col;
#pragma unroll
        for (int r = 0; r < 4; ++r) cp[(size_t)r * N] = f2bf(acc[mi][ni][r] * scale);
      }
    }
}

// ---------------------------------------------------------------------------
// Windowed attention. Grid = 256 blocks, 256 threads (4 waves).
// Block -> (b,h, qb): qb = 64-row slice of the 256 window-rows.
// Per (b,h): Q,K,V are [256 rows][Df=1024]; row w, col d=(p*64+e) lives at
// qkv[(b*4096 + w*16 + p)*3072 + s*1024 + h*64 + e], s in {0,1,2}.
// ---------------------------------------------------------------------------
__global__ __launch_bounds__(256) void attn_win(const u16* __restrict__ qkv,
                                                u16* __restrict__ attn) {
  const int bid = blockIdx.x;
  const int bh = (bid & 7) + ((bid >> 5) << 3);  // same bh -> same XCD (bid%8)
  const int qb = (bid >> 3) & 3;
  const int b = bh >> 4, h = bh & 15;

  const int tid = threadIdx.x;
  const int wv = tid >> 6, lane = tid & 63;
  const int fr = lane & 15, fg = lane >> 4;
  const int li = lane >> 2, lc = lane & 3;

  __shared__ alignas(16) char smem[33792 + 20480];
  u16* lP = (u16*)smem;                      // [64][264] bf16 P (persist ph2->ph3)
  u16* lQ = (u16*)(smem + 33792);            // [64][32]
  u16* lK = (u16*)(smem + 33792 + 4096);     // [256][32]
  float* redm = (float*)(smem + 33792);          // [4][64]
  float* reds = (float*)(smem + 33792 + 1024);   // [4][64]
  u16* lVt = (u16*)(smem + 33792);           // [256 n][40] V^T tile (32 x + pad)

  const size_t qbase = (size_t)b * 4096 * 3072;

  const f32x4 fz = {0.f, 0.f, 0.f, 0.f};
  f32x4 acc[4][4];
#pragma unroll
  for (int i = 0; i < 4; ++i)
#pragma unroll
    for (int j = 0; j < 4; ++j) acc[i][j] = fz;

  // ---- phase 1: S = Q K^T  (wave wv owns cols wv*64..+64, all 64 rows)
  for (int kt = 0; kt < 32; ++kt) {
    const size_t dofs = (size_t)(kt >> 1) * 3072 + h * 64 + (kt & 1) * 32 + lc * 8;
    {
      const int r = wv * 16 + li;  // q-row 0..63
      gld16(qkv + qbase + (size_t)((qb * 64 + r) * 16) * 3072 + dofs, lQ + wv * 512);
    }
#pragma unroll
    for (int j = 0; j < 4; ++j) {
      const int q = wv * 4 + j;
      const int r = q * 16 + li;  // k-row 0..255
      gld16(qkv + qbase + (size_t)(r * 16) * 3072 + 1024 + dofs, lK + q * 512);
    }
    __syncthreads();
    s16x8 qa[4];
#pragma unroll
    for (int mi = 0; mi < 4; ++mi)
      qa[mi] = *(const s16x8*)(lQ + (mi * 16 + fr) * 32 + fg * 8);
#pragma unroll
    for (int ni = 0; ni < 4; ++ni) {
      s16x8 kb = *(const s16x8*)(lK + (wv * 64 + ni * 16 + fr) * 32 + fg * 8);
#pragma unroll
      for (int mi = 0; mi < 4; ++mi)
        acc[mi][ni] = MFMA_BF16(qa[mi], kb, acc[mi][ni]);
    }
    __syncthreads();
  }

  // ---- phase 2: softmax over 256 cols; rows per lane: mi*16 + fg*4 + r
  float rmax[4][4], rnrm[4][4];
#pragma unroll
  for (int mi = 0; mi < 4; ++mi)
#pragma unroll
    for (int r = 0; r < 4; ++r) {
      float m = fmaxf(fmaxf(acc[mi][0][r], acc[mi][1][r]),
                      fmaxf(acc[mi][2][r], acc[mi][3][r]));
      for (int o = 1; o < 16; o <<= 1) m = fmaxf(m, __shfl_xor(m, o));
      rmax[mi][r] = m;
    }
  if (fr == 0) {
#pragma unroll
    for (int mi = 0; mi < 4; ++mi)
#pragma unroll
      for (int r = 0; r < 4; ++r) redm[wv * 64 + mi * 16 + fg * 4 + r] = rmax[mi][r];
  }
  __syncthreads();
#pragma unroll
  for (int mi = 0; mi < 4; ++mi)
#pragma unroll
    for (int r = 0; r < 4; ++r) {
      const int row = mi * 16 + fg * 4 + r;
      rmax[mi][r] = fmaxf(fmaxf(redm[row], redm[64 + row]),
                          fmaxf(redm[128 + row], redm[192 + row]));
    }
#pragma unroll
  for (int mi = 0; mi < 4; ++mi)
#pragma unroll
    for (int r = 0; r < 4; ++r) {
      float s = 0.f;
#pragma unroll
      for (int ni = 0; ni < 4; ++ni) {
        float p = exp2f((acc[mi][ni][r] - rmax[mi][r]) * 1.4426950408889634f);
        acc[mi][ni][r] = p;
        s += p;
      }
      for (int o = 1; o < 16; o <<= 1) s += __shfl_xor(s, o);
      rnrm[mi][r] = s;
    }
  if (fr == 0) {
#pragma unroll
    for (int mi = 0; mi < 4; ++mi)
#pragma unroll
      for (int r = 0; r < 4; ++r) reds[wv * 64 + mi * 16 + fg * 4 + r] = rnrm[mi][r];
  }
  __syncthreads();
#pragma unroll
  for (int mi = 0; mi < 4; ++mi)
#pragma unroll
    for (int r = 0; r < 4; ++r) {
      const int row = mi * 16 + fg * 4 + r;
      rnrm[mi][r] = 1.f / (reds[row] + reds[64 + row] + reds[128 + row] + reds[192 + row]);
    }
#pragma unroll
  for (int mi = 0; mi < 4; ++mi)
#pragma unroll
    for (int ni = 0; ni < 4; ++ni)
#pragma unroll
      for (int r = 0; r < 4; ++r)
        lP[(mi * 16 + fg * 4 + r) * 264 + wv * 64 + ni * 16 + fr] =
            f2bf(acc[mi][ni][r] * rnrm[mi][r]);
  __syncthreads();  // lP ready; redm/reds region freed for lVt

  // ---- phase 3: O = P V, n-chunks of 256 cols, k(x)-tiles of 32
#pragma unroll 1
  for (int nc = 0; nc < 4; ++nc) {
    f32x4 oacc[4][4];
#pragma unroll
    for (int i = 0; i < 4; ++i)
#pragma unroll
      for (int j = 0; j < 4; ++j) oacc[i][j] = fz;
#pragma unroll 1
    for (int xt = 0; xt < 8; ++xt) {
      // stage V^T tile: [32 x][256 n] -> lVt[n][40] (x at 0..31, pad to 40)
#pragma unroll
      for (int it = 0; it < 4; ++it) {
        const int id = it * 256 + tid;
        const int xl = id & 31, ng = id >> 5;
        const int d = nc * 256 + ng * 8;
        const u16* g = qkv + qbase +
                       (size_t)((xt * 32 + xl) * 16 + (d >> 6)) * 3072 + 2048 +
                       h * 64 + (d & 63);
        s16x8 v = *(const s16x8*)g;
#pragma unroll
        for (int i = 0; i < 8; ++i) lVt[(ng * 8 + i) * 40 + xl] = (u16)v[i];
      }
      __syncthreads();
      s16x8 pa[4];
#pragma unroll
      for (int mi = 0; mi < 4; ++mi)
        pa[mi] = *(const s16x8*)(lP + (mi * 16 + fr) * 264 + xt * 32 + fg * 8);
#pragma unroll
      for (int ni = 0; ni < 4; ++ni) {
        s16x8 vb = *(const s16x8*)(lVt + (wv * 64 + ni * 16 + fr) * 40 + fg * 8);
#pragma unroll
        for (int mi = 0; mi < 4; ++mi)
          oacc[mi][ni] = MFMA_BF16(pa[mi], vb, oacc[mi][ni]);
      }
      __syncthreads();
    }
    // store O chunk -> attn_out token layout [B,N,H*hd]
#pragma unroll
    for (int mi = 0; mi < 4; ++mi)
#pragma unroll
      for (int ni = 0; ni < 4; ++ni) {
        const int row = mi * 16 + fg * 4;
        const int d = nc * 256 + wv * 64 + ni * 16 + fr;
        const int p = d >> 6, e = d & 63;
        const size_t base =
            (size_t)(b * 4096 + (qb * 64 + row) * 16 + p) * 1024 + h * 64 + e;
#pragma unroll
        for (int r = 0; r < 4; ++r)
          attn[base + (size_t)r * 16 * 1024] = f2bf(oacc[mi][ni][r]);
      }
  }
}

// ---------------------------------------------------------------------------
extern "C" void kernel_launch(void* const* d_in, const int* in_sizes, int n_in,
                              void* d_out, int out_size, void* d_ws, size_t ws_size,
                              hipStream_t stream) {
  (void)in_sizes; (void)n_in; (void)out_size; (void)ws_size;
  const float* x = (const float*)d_in[0];      // [16384,1024] f32
  const float* wqkv = (const float*)d_in[1];   // [3072,1024] f32
  const float* wproj = (const float*)d_in[2];  // [1024,1024] f32
  float* out = (float*)d_out;                  // [16384,1024] f32

  char* ws = (char*)d_ws;
  u16* qkv = (u16*)ws;                          // [16384,3072] bf16 (100.7 MB)
  u16* xbf = (u16*)(ws + 100663296);            // [16384,1024] bf16 (33.6 MB)
  u16* attn = xbf;                              // reuse: xbf dead after gemm1
  u16* wqkvb = (u16*)(ws + 134217728);          // [3072,1024] bf16 (6.3 MB)
  u16* wprojb = (u16*)(ws + 140509184);         // [1024,1024] bf16 (2.1 MB)

  cvt_bf16<<<2048, 256, 0, stream>>>(x, xbf, 16777216 / 8);
  cvt_bf16<<<1536, 256, 0, stream>>>(wqkv, wqkvb, 3145728 / 8);
  cvt_bf16<<<512, 256, 0, stream>>>(wproj, wprojb, 1048576 / 8);

  gemm256<true, false, 12><<<768, 512, 0, stream>>>(xbf, wqkvb, qkv);
  attn_win<<<256, 256, 0, stream>>>(qkv, attn);
  gemm256<false, true, 4><<<256, 512, 0, stream>>>(attn, wprojb, out);
}

// Round 9
// 219.250 us; speedup vs baseline: 6.8130x; 1.0928x over previous
//
#include <hip/hip_runtime.h>
#include <hip/hip_bf16.h>
#include <stdint.h>

// SlidingWindowAttention: x[4,4096,1024] f32, Wqkv[3072,1024] f32, Wproj[1024,1024] f32
// I/O f32; internal bf16 (MFMA) with f32 accum.
// qkv = x@Wqkv^T (q*=0.125 fused) -> per (b,h) flattened-window attention
// (256x256 over Df=1024) -> out = attn_out @ Wproj^T (f32 out).

using u16 = unsigned short;
typedef __attribute__((ext_vector_type(4))) float f32x4;
typedef __attribute__((ext_vector_type(8))) short s16x8;

#define MFMA_BF16(a, b, c) __builtin_amdgcn_mfma_f32_16x16x32_bf16((a), (b), (c), 0, 0, 0)

__device__ __forceinline__ u16 f2bf(float f) {
  union { float f; uint32_t u; } v; v.f = f;
  uint32_t r = v.u + 0x7fffu + ((v.u >> 16) & 1u);  // RNE
  return (u16)(r >> 16);
}

// async global->LDS, 16B per lane; LDS dest is wave-uniform base + lane*16
__device__ __forceinline__ void gld16(const void* g, void* l) {
  auto gp = (const __attribute__((address_space(1))) void*)(uintptr_t)g;
  auto lp = (__attribute__((address_space(3))) void*)(uint32_t)(uintptr_t)l;
  __builtin_amdgcn_global_load_lds(gp, lp, 16, 0, 0);
}

// ---------------------------------------------------------------------------
// f32 -> bf16 convert for all three inputs in one launch (8 elems/thread/iter)
// segments (in 8-elem units): x 2,097,152 | wqkv 393,216 | wproj 131,072
// ---------------------------------------------------------------------------
__global__ __launch_bounds__(256) void cvt3(const float* __restrict__ x,
                                            const float* __restrict__ w1,
                                            const float* __restrict__ w2,
                                            u16* __restrict__ ox,
                                            u16* __restrict__ ow1,
                                            u16* __restrict__ ow2) {
  const int stride = gridDim.x * blockDim.x;
  for (int i = blockIdx.x * blockDim.x + threadIdx.x; i < 2621440; i += stride) {
    const float* src; u16* dst; int j;
    if (i < 2097152)      { src = x;  dst = ox;  j = i; }
    else if (i < 2490368) { src = w1; dst = ow1; j = i - 2097152; }
    else                  { src = w2; dst = ow2; j = i - 2490368; }
    const float4* p = (const float4*)src + (size_t)j * 2;
    float4 a = p[0], b = p[1];
    s16x8 r;
    r[0] = (short)f2bf(a.x); r[1] = (short)f2bf(a.y);
    r[2] = (short)f2bf(a.z); r[3] = (short)f2bf(a.w);
    r[4] = (short)f2bf(b.x); r[5] = (short)f2bf(b.y);
    r[6] = (short)f2bf(b.z); r[7] = (short)f2bf(b.w);
    *(s16x8*)(dst + (size_t)j * 8) = r;
  }
}

// ---------------------------------------------------------------------------
// 256x256-tile GEMM (UNCHANGED from round 7 - verified). See r7 notes.
// ---------------------------------------------------------------------------
template <bool QS, bool F32OUT, int GN>
__global__ __launch_bounds__(512, 2) void gemm256(const u16* __restrict__ A,
                                                  const u16* __restrict__ W,
                                                  void* __restrict__ C) {
  __shared__ alignas(16) u16 lds[4 * 16384];  // 4 x (A 16KB + B 16KB)
  const int tid = threadIdx.x;
  const int wv = tid >> 6, lane = tid & 63;
  const int fr = lane & 15, fg = lane >> 4;
  const int wm = wv >> 2, wn = wv & 3;
  const int N = GN * 256;

  const int nwg = 64 * GN;
  const int p = blockIdx.x;
  const int logical = (p & 7) * (nwg >> 3) + (p >> 3);
  const int bm = logical / GN, bn = logical % GN;

  const int srow = tid >> 2;
  const int skg = (tid & 3) ^ ((tid >> 3) & 3);

  const u16* As = A + (size_t)(bm * 256 + srow) * 1024 + skg * 8;
  const u16* Ws = W + (size_t)(bn * 256 + srow) * 1024 + skg * 8;

  const f32x4 fz = {0.f, 0.f, 0.f, 0.f};
  f32x4 acc[8][4];
#pragma unroll
  for (int i = 0; i < 8; ++i)
#pragma unroll
    for (int j = 0; j < 4; ++j) acc[i][j] = fz;

  auto STAGE_A = [&](int t) {
    u16* dst = lds + (t & 3) * 16384;
    const int k0 = t * 32;
    gld16(As + k0,          dst + wv * 512);
    gld16(As + 131072 + k0, dst + 4096 + wv * 512);
  };
  auto STAGE_B = [&](int t) {
    u16* dst = lds + (t & 3) * 16384;
    const int k0 = t * 32;
    gld16(Ws + k0,          dst + 8192 + wv * 512);
    gld16(Ws + 131072 + k0, dst + 12288 + wv * 512);
  };

  STAGE_A(0); STAGE_B(0);
  STAGE_A(1); STAGE_B(1);
  STAGE_A(2); STAGE_B(2);
  asm volatile("s_waitcnt vmcnt(8)" ::: "memory");
  __builtin_amdgcn_s_barrier();

  const int rsw = (fg ^ ((fr >> 1) & 3)) * 8;
  const int aoff = (wm * 128 + fr) * 32 + rsw;
  const int boff = 8192 + (wn * 64 + fr) * 32 + rsw;

  for (int t = 0; t < 32; ++t) {
    const u16* buf = lds + (t & 3) * 16384;
    s16x8 a0[4], a1[4], bv[4];

#pragma unroll
    for (int mi = 0; mi < 4; ++mi)
      a0[mi] = *(const s16x8*)(buf + aoff + mi * 512);
#pragma unroll
    for (int ni = 0; ni < 4; ++ni)
      bv[ni] = *(const s16x8*)(buf + boff + ni * 512);
    __builtin_amdgcn_sched_barrier(0);
#pragma unroll
    for (int mi = 0; mi < 4; ++mi)
      a1[mi] = *(const s16x8*)(buf + aoff + (4 + mi) * 512);

    if (t <= 28) {
      STAGE_A(t + 3);
      asm volatile("s_waitcnt vmcnt(6)" ::: "memory");
    } else if (t == 29) {
      asm volatile("s_waitcnt vmcnt(4)" ::: "memory");
    } else {
      asm volatile("s_waitcnt vmcnt(0)" ::: "memory");
    }
    __builtin_amdgcn_s_barrier();

    asm volatile("s_waitcnt lgkmcnt(4)" ::: "memory");
    __builtin_amdgcn_sched_barrier(0);
    __builtin_amdgcn_s_setprio(1);
#pragma unroll
    for (int ni = 0; ni < 4; ++ni)
#pragma unroll
      for (int mi = 0; mi < 4; ++mi)
        acc[mi][ni] = MFMA_BF16(a0[mi], bv[ni], acc[mi][ni]);
    __builtin_amdgcn_s_setprio(0);

    if (t <= 28) STAGE_B(t + 3);
    asm volatile("s_waitcnt lgkmcnt(0)" ::: "memory");
    __builtin_amdgcn_sched_barrier(0);
    __builtin_amdgcn_s_barrier();

    __builtin_amdgcn_s_setprio(1);
#pragma unroll
    for (int ni = 0; ni < 4; ++ni)
#pragma unroll
      for (int mi = 0; mi < 4; ++mi)
        acc[4 + mi][ni] = MFMA_BF16(a1[mi], bv[ni], acc[4 + mi][ni]);
    __builtin_amdgcn_s_setprio(0);
  }

  const float scale = (QS && bn < 4) ? 0.125f : 1.0f;
#pragma unroll
  for (int mi = 0; mi < 8; ++mi)
#pragma unroll
    for (int ni = 0; ni < 4; ++ni) {
      const int row = bm * 256 + wm * 128 + mi * 16 + fg * 4;
      const int col = bn * 256 + wn * 64 + ni * 16 + fr;
      if (F32OUT) {
        float* cp = (float*)C + (size_t)row * N + col;
#pragma unroll
        for (int r = 0; r < 4; ++r) cp[(size_t)r * N] = acc[mi][ni][r] * scale;
      } else {
        u16* cp = (u16*)C + (size_t)row * N + col;
#pragma unroll
        for (int r = 0; r < 4; ++r) cp[(size_t)r * N] = f2bf(acc[mi][ni][r] * scale);
      }
    }
}

// ---------------------------------------------------------------------------
// Windowed attention v2. Grid = 256 blocks, 512 threads (8 waves, 2/SIMD).
// Block -> (b,h,qb): 64 q-rows x 256 k-cols. QK^T: wave wv owns cols wv*32
// (2 n-frags); K/Q staged per-BK32 with the r5/r6-verified single-barrier
// double-buffer + T2 swizzle (same [row][32u16] geometry as gemm256).
// PV: V^T staged via column-strided ushort reads (coalesced 128B/wave/row,
// L2-resident) + ONE ds_write_b128 per octet (8x fewer LDS ops than the old
// scalar-store transpose), double-buffered lVt, loads issued pre-MFMA (T14).
// LDS map (bytes): lP [64][264] @0 (33792); SB=33792: QK^T dbuf
// {lQ[2]:4KB each, lK[2]:16KB each} = 40KB; after QK^T the SB region is
// reused: redm/reds [8][64]f32 (4KB), then lVt dbuf 2x20480. Total 74752.
// NOTE: no pointer-array of LDS addresses (gfx950 clang rejects the static
// addrspacecast initializer) - two named pointers + ternary instead.
// ---------------------------------------------------------------------------
__global__ __launch_bounds__(512) void attn_win(const u16* __restrict__ qkv,
                                                u16* __restrict__ attn) {
  const int bid = blockIdx.x;
  const int bh = (bid & 7) + ((bid >> 5) << 3);  // same bh -> same XCD (bid%8)
  const int qb = (bid >> 3) & 3;
  const int b = bh >> 4, h = bh & 15;

  const int tid = threadIdx.x;
  const int wv = tid >> 6, lane = tid & 63;
  const int fr = lane & 15, fg = lane >> 4;

  __shared__ alignas(16) char smem[74752];
  u16* lP = (u16*)smem;                        // [64][264]
  const int SB = 33792;
  float* redm = (float*)(smem + SB);           // [8][64]
  float* reds = (float*)(smem + SB + 2048);    // [8][64]

  const size_t qbase = (size_t)b * 4096 * 3072;
  const int sg = (lane & 3) ^ ((lane >> 3) & 3);  // inverse-swz source granule

  // staging sources (T2: linear LDS dest, inverse-swizzled global source)
  const int krow = tid >> 2;                      // 0..127
  const u16* Ksrc = qkv + qbase + (size_t)(krow * 16) * 3072 + 1024 + h * 64 + sg * 8;
  const int qrow = (wv & 3) * 16 + (lane >> 2);   // 0..63 (waves 0-3)
  const u16* Qsrc = qkv + qbase + (size_t)((qb * 64 + qrow) * 16) * 3072 + h * 64 + sg * 8;

  auto STAGE_QK = [&](int t) {
    u16* qd = (u16*)(smem + SB + (t & 1) * 4096);
    u16* kd = (u16*)(smem + SB + 8192 + (t & 1) * 16384);
    const int dofs = (t >> 1) * 3072 + (t & 1) * 32;
    gld16(Ksrc + dofs, kd + wv * 512);
    gld16(Ksrc + (size_t)128 * 16 * 3072 + dofs, kd + 4096 + wv * 512);
    if (wv < 4) gld16(Qsrc + dofs, qd + wv * 512);
  };

  const f32x4 fz = {0.f, 0.f, 0.f, 0.f};
  f32x4 acc[4][2];
#pragma unroll
  for (int i = 0; i < 4; ++i)
#pragma unroll
    for (int j = 0; j < 2; ++j) acc[i][j] = fz;

  const int rsw = (fg ^ ((fr >> 1) & 3)) * 8;  // swizzled read granule

  // ---- phase 1: S = Q K^T (single-barrier dbuf, verified template) ----
  STAGE_QK(0);
  asm volatile("s_waitcnt vmcnt(0)" ::: "memory");
  __builtin_amdgcn_s_barrier();

  for (int kt = 0; kt < 32; ++kt) {
    const u16* qbuf = (const u16*)(smem + SB + (kt & 1) * 4096);
    const u16* kbuf = (const u16*)(smem + SB + 8192 + (kt & 1) * 16384);
    if (kt < 31) STAGE_QK(kt + 1);

    s16x8 qa[4], kb[2];
#pragma unroll
    for (int mi = 0; mi < 4; ++mi)
      qa[mi] = *(const s16x8*)(qbuf + (mi * 16 + fr) * 32 + rsw);
#pragma unroll
    for (int ni = 0; ni < 2; ++ni)
      kb[ni] = *(const s16x8*)(kbuf + (wv * 32 + ni * 16 + fr) * 32 + rsw);

    asm volatile("s_waitcnt lgkmcnt(0)" ::: "memory");
    __builtin_amdgcn_sched_barrier(0);
    __builtin_amdgcn_s_setprio(1);
#pragma unroll
    for (int ni = 0; ni < 2; ++ni)
#pragma unroll
      for (int mi = 0; mi < 4; ++mi)
        acc[mi][ni] = MFMA_BF16(qa[mi], kb[ni], acc[mi][ni]);
    __builtin_amdgcn_s_setprio(0);

    if (kt < 31) {
      asm volatile("s_waitcnt vmcnt(0)" ::: "memory");
      __builtin_amdgcn_s_barrier();
    }
  }
  __syncthreads();  // staging region freed for redm/reds overlay

  // ---- phase 2: softmax (rows mi*16+fg*4+r; cols wv*32+ni*16+fr) ----
  float rmax[4][4], rnrm[4][4];
#pragma unroll
  for (int mi = 0; mi < 4; ++mi)
#pragma unroll
    for (int r = 0; r < 4; ++r) {
      float m = fmaxf(acc[mi][0][r], acc[mi][1][r]);
      for (int o = 1; o < 16; o <<= 1) m = fmaxf(m, __shfl_xor(m, o));
      rmax[mi][r] = m;
    }
  if (fr == 0) {
#pragma unroll
    for (int mi = 0; mi < 4; ++mi)
#pragma unroll
      for (int r = 0; r < 4; ++r) redm[wv * 64 + mi * 16 + fg * 4 + r] = rmax[mi][r];
  }
  __syncthreads();
#pragma unroll
  for (int mi = 0; mi < 4; ++mi)
#pragma unroll
    for (int r = 0; r < 4; ++r) {
      const int row = mi * 16 + fg * 4 + r;
      float m = redm[row];
#pragma unroll
      for (int w = 1; w < 8; ++w) m = fmaxf(m, redm[w * 64 + row]);
      rmax[mi][r] = m;
    }
#pragma unroll
  for (int mi = 0; mi < 4; ++mi)
#pragma unroll
    for (int r = 0; r < 4; ++r) {
      float s = 0.f;
#pragma unroll
      for (int ni = 0; ni < 2; ++ni) {
        float p = exp2f((acc[mi][ni][r] - rmax[mi][r]) * 1.4426950408889634f);
        acc[mi][ni][r] = p;
        s += p;
      }
      for (int o = 1; o < 16; o <<= 1) s += __shfl_xor(s, o);
      rnrm[mi][r] = s;
    }
  __syncthreads();  // redm reads done before reds overlay region reuse is safe
  if (fr == 0) {
#pragma unroll
    for (int mi = 0; mi < 4; ++mi)
#pragma unroll
      for (int r = 0; r < 4; ++r) reds[wv * 64 + mi * 16 + fg * 4 + r] = rnrm[mi][r];
  }
  __syncthreads();
#pragma unroll
  for (int mi = 0; mi < 4; ++mi)
#pragma unroll
    for (int r = 0; r < 4; ++r) {
      const int row = mi * 16 + fg * 4 + r;
      float s = reds[row];
#pragma unroll
      for (int w = 1; w < 8; ++w) s += reds[w * 64 + row];
      rnrm[mi][r] = 1.f / s;
    }
#pragma unroll
  for (int mi = 0; mi < 4; ++mi)
#pragma unroll
    for (int ni = 0; ni < 2; ++ni)
#pragma unroll
      for (int r = 0; r < 4; ++r)
        lP[(mi * 16 + fg * 4 + r) * 264 + wv * 32 + ni * 16 + fr] =
            f2bf(acc[mi][ni][r] * rnrm[mi][r]);
  __syncthreads();  // lP ready; SB region freed for lVt dbuf

  // ---- phase 3: O = P V ----
  u16* lVt0 = (u16*)(smem + SB);
  u16* lVt1 = (u16*)(smem + SB + 20480);
  const int ld = tid & 255;       // local d-col 0..255
  const int jb = tid >> 8;        // x-octet selector 0/1

  for (int nc = 0; nc < 4; ++nc) {
    const int d = nc * 256 + ld;
    const u16* Vcol = qkv + qbase + (size_t)(d >> 6) * 3072 + 2048 + h * 64 + (d & 63);

    f32x4 oacc[4][2];
#pragma unroll
    for (int i = 0; i < 4; ++i)
#pragma unroll
      for (int j = 0; j < 2; ++j) oacc[i][j] = fz;

    u16 va[2][8];
    auto VLOAD = [&](int xt) {
#pragma unroll
      for (int jj = 0; jj < 2; ++jj) {
        const int xo = (jb + 2 * jj) * 8;
        const u16* g = Vcol + (size_t)((xt * 32 + xo) * 16) * 3072;
#pragma unroll
        for (int i = 0; i < 8; ++i) va[jj][i] = g[(size_t)i * 16 * 3072];
      }
    };
    auto VWRITE = [&](u16* buf) {
#pragma unroll
      for (int jj = 0; jj < 2; ++jj) {
        const int xo = (jb + 2 * jj) * 8;
        s16x8 v;
#pragma unroll
        for (int i = 0; i < 8; ++i) v[i] = (short)va[jj][i];
        *(s16x8*)(buf + ld * 40 + xo) = v;
      }
    };

    VLOAD(0);
    VWRITE(lVt0);  // prologue: lVt0 free (prev nc's last reads pre-barrier)

#pragma unroll 1
    for (int xt = 0; xt < 8; ++xt) {
      u16* cur = (xt & 1) ? lVt1 : lVt0;
      u16* nxt = (xt & 1) ? lVt0 : lVt1;
      __syncthreads();  // cur writes visible; nxt's old readers done

      if (xt < 7) VLOAD(xt + 1);  // issue early; lands under MFMA (T14)

      s16x8 pa[4], vb[2];
#pragma unroll
      for (int mi = 0; mi < 4; ++mi)
        pa[mi] = *(const s16x8*)(lP + (mi * 16 + fr) * 264 + xt * 32 + fg * 8);
#pragma unroll
      for (int ni = 0; ni < 2; ++ni)
        vb[ni] = *(const s16x8*)(cur + (wv * 32 + ni * 16 + fr) * 40 + fg * 8);

      asm volatile("s_waitcnt lgkmcnt(0)" ::: "memory");
      __builtin_amdgcn_sched_barrier(0);
      __builtin_amdgcn_s_setprio(1);
#pragma unroll
      for (int ni = 0; ni < 2; ++ni)
#pragma unroll
        for (int mi = 0; mi < 4; ++mi)
          oacc[mi][ni] = MFMA_BF16(pa[mi], vb[ni], oacc[mi][ni]);
      __builtin_amdgcn_s_setprio(0);

      if (xt < 7) VWRITE(nxt);
    }
    __syncthreads();  // all reads done before next nc's prologue VWRITE

    // store O chunk -> token layout [B,N,H*hd]
#pragma unroll
    for (int mi = 0; mi < 4; ++mi)
#pragma unroll
      for (int ni = 0; ni < 2; ++ni) {
        const int row = mi * 16 + fg * 4;
        const int dd = nc * 256 + wv * 32 + ni * 16 + fr;
        const int pp = dd >> 6, e = dd & 63;
        const size_t base =
            (size_t)(b * 4096 + (qb * 64 + row) * 16 + pp) * 1024 + h * 64 + e;
#pragma unroll
        for (int r = 0; r < 4; ++r)
          attn[base + (size_t)r * 16 * 1024] = f2bf(oacc[mi][ni][r]);
      }
  }
}

// ---------------------------------------------------------------------------
extern "C" void kernel_launch(void* const* d_in, const int* in_sizes, int n_in,
                              void* d_out, int out_size, void* d_ws, size_t ws_size,
                              hipStream_t stream) {
  (void)in_sizes; (void)n_in; (void)out_size; (void)ws_size;
  const float* x = (const float*)d_in[0];      // [16384,1024] f32
  const float* wqkv = (const float*)d_in[1];   // [3072,1024] f32
  const float* wproj = (const float*)d_in[2];  // [1024,1024] f32
  float* out = (float*)d_out;                  // [16384,1024] f32

  char* ws = (char*)d_ws;
  u16* qkv = (u16*)ws;                          // [16384,3072] bf16 (100.7 MB)
  u16* xbf = (u16*)(ws + 100663296);            // [16384,1024] bf16 (33.6 MB)
  u16* attn = xbf;                              // reuse: xbf dead after gemm1
  u16* wqkvb = (u16*)(ws + 134217728);          // [3072,1024] bf16 (6.3 MB)
  u16* wprojb = (u16*)(ws + 140509184);         // [1024,1024] bf16 (2.1 MB)

  cvt3<<<2048, 256, 0, stream>>>(x, wqkv, wproj, xbf, wqkvb, wprojb);
  gemm256<true, false, 12><<<768, 512, 0, stream>>>(xbf, wqkvb, qkv);
  attn_win<<<256, 512, 0, stream>>>(qkv, attn);
  gemm256<false, true, 4><<<256, 512, 0, stream>>>(attn, wprojb, out);
}